// Round 2
// baseline (592.639 us; speedup 1.0000x reference)
//
#include <hip/hip_runtime.h>

#define NBATCH 1024
#define N0     25
#define N1     10
#define NLEAF  (N0 * N1)   // 250
// embedding dim = 128 f32; one row = 512 B = 32 float4

__global__ __launch_bounds__(256) void sage_fused(
    const float* __restrict__ emb,    // [NODE_CNT+1][128] f32
    const float* __restrict__ W0,     // [256][128] f32
    const float* __restrict__ b0,     // [128] f32
    const float* __restrict__ W1,     // [256][128] f32
    const int* __restrict__ roots,    // [B]
    const int* __restrict__ idx1,     // [B][25]
    const int* __restrict__ idx2,     // [B][25][10]
    float* __restrict__ out)          // [B][128] f32
{
    const int b    = blockIdx.x;
    const int tid  = threadIdx.x;
    const int slot = tid >> 4;   // 0..15 : row slot
    const int cc   = tid & 15;   // 0..15 : 32-byte column chunk (cols 8*cc .. 8*cc+7)

    __shared__ float red[16][128];   // cross-slot reduce buffer (8 KB)
    __shared__ float hr[128];        // root embedding
    __shared__ float m1[128];        // mean over idx1 rows
    __shared__ float m2[128];        // mean over idx2 rows
    __shared__ float tv[128];        // mean0 = concat(m1,m2) @ W1

    const float4* embq = (const float4*)emb;  // row r = embq[r*32 .. r*32+31]

    // ---------------- phase 1a: idx2 gather (250 rows), mean -> m2 ----------
    float acc[8];
#pragma unroll
    for (int j = 0; j < 8; ++j) acc[j] = 0.f;
    for (int k = slot; k < NLEAF; k += 16) {
        int id = idx2[b * NLEAF + k];
        const float4* p = embq + (size_t)id * 32 + cc * 2;
        float4 v0 = p[0];
        float4 v1 = p[1];
        acc[0] += v0.x; acc[1] += v0.y; acc[2] += v0.z; acc[3] += v0.w;
        acc[4] += v1.x; acc[5] += v1.y; acc[6] += v1.z; acc[7] += v1.w;
    }
#pragma unroll
    for (int j = 0; j < 8; ++j) red[slot][cc * 8 + j] = acc[j];
    __syncthreads();
    if (tid < 128) {
        float s = 0.f;
#pragma unroll
        for (int g = 0; g < 16; ++g) s += red[g][tid];
        m2[tid] = s * (1.0f / NLEAF);
    }
    __syncthreads();

    // ---------------- phase 1b: idx1 gather (25 rows) -> m1; root -> hr -----
#pragma unroll
    for (int j = 0; j < 8; ++j) acc[j] = 0.f;
    for (int k = slot; k < N0; k += 16) {
        int id = idx1[b * N0 + k];
        const float4* p = embq + (size_t)id * 32 + cc * 2;
        float4 v0 = p[0];
        float4 v1 = p[1];
        acc[0] += v0.x; acc[1] += v0.y; acc[2] += v0.z; acc[3] += v0.w;
        acc[4] += v1.x; acc[5] += v1.y; acc[6] += v1.z; acc[7] += v1.w;
    }
#pragma unroll
    for (int j = 0; j < 8; ++j) red[slot][cc * 8 + j] = acc[j];
    if (slot == 0) {
        int id = roots[b];
        const float4* p = embq + (size_t)id * 32 + cc * 2;
        float4 v0 = p[0];
        float4 v1 = p[1];
        hr[cc * 8 + 0] = v0.x; hr[cc * 8 + 1] = v0.y;
        hr[cc * 8 + 2] = v0.z; hr[cc * 8 + 3] = v0.w;
        hr[cc * 8 + 4] = v1.x; hr[cc * 8 + 5] = v1.y;
        hr[cc * 8 + 6] = v1.z; hr[cc * 8 + 7] = v1.w;
    }
    __syncthreads();
    if (tid < 128) {
        float s = 0.f;
#pragma unroll
        for (int g = 0; g < 16; ++g) s += red[g][tid];
        m1[tid] = s * (1.0f / N0);
    }
    __syncthreads();

    // ---------------- phase 2a: tv = concat(m1, m2) @ W1  (256 -> 128) ------
    // split-K: h = tid>>7 selects k-half; c = tid&127 is output column
    const int c = tid & 127;
    const int h = tid >> 7;
    {
        const float* xh = h ? m2 : m1;
        const float* w = W1 + (size_t)(h * 128) * 128 + c;
        float p = 0.f;
#pragma unroll 8
        for (int k = 0; k < 128; ++k) {
            p += xh[k] * w[(size_t)k * 128];
        }
        red[h][c] = p;
    }
    __syncthreads();
    if (tid < 128) tv[tid] = red[0][tid] + red[1][tid];
    __syncthreads();

    // ---------------- phase 2b: z = concat(hr, tv) @ W0 + b0; sigmoid -------
    {
        const float* yh = h ? tv : hr;
        const float* w = W0 + (size_t)(h * 128) * 128 + c;
        float q = 0.f;
#pragma unroll 8
        for (int k = 0; k < 128; ++k) {
            q += yh[k] * w[(size_t)k * 128];
        }
        red[h][c] = q;
    }
    __syncthreads();
    if (tid < 128) {
        float z = red[0][tid] + red[1][tid] + b0[tid];
        float s = 1.0f / (1.0f + __expf(-z));
        out[(size_t)b * 128 + tid] = s;
    }
}

extern "C" void kernel_launch(void* const* d_in, const int* in_sizes, int n_in,
                              void* d_out, int out_size, void* d_ws, size_t ws_size,
                              hipStream_t stream) {
    const float* emb   = (const float*)d_in[0];
    const float* W0    = (const float*)d_in[1];
    const float* b0    = (const float*)d_in[2];
    const float* W1    = (const float*)d_in[3];
    const int*   roots = (const int*)d_in[4];
    const int*   idx1  = (const int*)d_in[5];
    const int*   idx2  = (const int*)d_in[6];
    float* out = (float*)d_out;

    sage_fused<<<NBATCH, 256, 0, stream>>>(emb, W0, b0, W1, roots, idx1, idx2, out);
}

// Round 3
// 588.536 us; speedup vs baseline: 1.0070x; 1.0070x over previous
//
#include <hip/hip_runtime.h>

#define NBATCH 1024
#define N0     25
#define N1     10
#define NLEAF  (N0 * N1)   // 250
// embedding dim = 128 f32; one row = 512 B = 32 float4

__global__ __launch_bounds__(256) void sage_fused(
    const float* __restrict__ emb,    // [NODE_CNT+1][128] f32
    const float* __restrict__ W0,     // [256][128] f32
    const float* __restrict__ b0,     // [128] f32
    const float* __restrict__ W1,     // [256][128] f32
    const int* __restrict__ roots,    // [B]
    const int* __restrict__ idx1,     // [B][25]
    const int* __restrict__ idx2,     // [B][25][10]
    float* __restrict__ out)          // [B][128] f32
{
    const int b    = blockIdx.x;
    const int tid  = threadIdx.x;
    const int slot = tid >> 4;   // 0..15 : row slot
    const int cc   = tid & 15;   // 0..15 : 32-byte column chunk (cols 8*cc..8*cc+7)

    __shared__ int   sidx2[NLEAF];   // all 2-hop indices for this batch row
    __shared__ int   sidx1[N0];
    __shared__ float red[16][128];   // cross-slot reduce buffer (8 KB)
    __shared__ float hr[128];        // root embedding
    __shared__ float m1[128];        // mean over idx1 rows
    __shared__ float m2[128];        // mean over idx2 rows
    __shared__ float tv[128];        // mean0 = concat(m1,m2) @ W1
    __shared__ int   sroot;

    // ---- phase 0: stage all indices into LDS (coalesced, one shot) --------
    if (tid < NLEAF) sidx2[tid] = idx2[b * NLEAF + tid];
    if (tid >= 231)  sidx1[tid - 231] = idx1[b * N0 + (tid - 231)];  // 25 loads
    if (tid == 0)    sroot = roots[b];
    __syncthreads();

    const float4* embq = (const float4*)emb;  // row r = embq[r*32 .. r*32+31]

    // ---- phase 1a: idx2 gather (250 rows), mean -> m2 ----------------------
    // slot s handles k = s, s+16, ...  -> 15 full iterations (k <= 239 < 250
    // always valid), then a predicated tail for slots 0..9.
    float acc[8];
#pragma unroll
    for (int j = 0; j < 8; ++j) acc[j] = 0.f;
#pragma unroll 5
    for (int i = 0; i < 15; ++i) {
        int id = sidx2[slot + 16 * i];
        const float4* p = embq + (size_t)id * 32 + cc * 2;
        float4 v0 = p[0];
        float4 v1 = p[1];
        acc[0] += v0.x; acc[1] += v0.y; acc[2] += v0.z; acc[3] += v0.w;
        acc[4] += v1.x; acc[5] += v1.y; acc[6] += v1.z; acc[7] += v1.w;
    }
    if (slot < 10) {                 // tail: k = slot + 240 (240..249)
        int id = sidx2[slot + 240];
        const float4* p = embq + (size_t)id * 32 + cc * 2;
        float4 v0 = p[0];
        float4 v1 = p[1];
        acc[0] += v0.x; acc[1] += v0.y; acc[2] += v0.z; acc[3] += v0.w;
        acc[4] += v1.x; acc[5] += v1.y; acc[6] += v1.z; acc[7] += v1.w;
    }
#pragma unroll
    for (int j = 0; j < 8; ++j) red[slot][cc * 8 + j] = acc[j];
    __syncthreads();
    if (tid < 128) {
        float s = 0.f;
#pragma unroll
        for (int g = 0; g < 16; ++g) s += red[g][tid];
        m2[tid] = s * (1.0f / NLEAF);
    }
    __syncthreads();

    // ---- phase 1b: idx1 gather (25 rows) -> m1; root row -> hr -------------
    // iter 0: k = slot (0..15, all < 25). tail: slots 0..8 -> k = slot+16
    // (16..24); slot 15 (idle in tail) loads the root row instead.
#pragma unroll
    for (int j = 0; j < 8; ++j) acc[j] = 0.f;
    {
        int id = sidx1[slot];
        const float4* p = embq + (size_t)id * 32 + cc * 2;
        float4 v0 = p[0];
        float4 v1 = p[1];
        acc[0] += v0.x; acc[1] += v0.y; acc[2] += v0.z; acc[3] += v0.w;
        acc[4] += v1.x; acc[5] += v1.y; acc[6] += v1.z; acc[7] += v1.w;
    }
    if (slot < 9) {
        int id = sidx1[slot + 16];
        const float4* p = embq + (size_t)id * 32 + cc * 2;
        float4 v0 = p[0];
        float4 v1 = p[1];
        acc[0] += v0.x; acc[1] += v0.y; acc[2] += v0.z; acc[3] += v0.w;
        acc[4] += v1.x; acc[5] += v1.y; acc[6] += v1.z; acc[7] += v1.w;
    } else if (slot == 15) {
        const float4* p = embq + (size_t)sroot * 32 + cc * 2;
        float4 v0 = p[0];
        float4 v1 = p[1];
        hr[cc * 8 + 0] = v0.x; hr[cc * 8 + 1] = v0.y;
        hr[cc * 8 + 2] = v0.z; hr[cc * 8 + 3] = v0.w;
        hr[cc * 8 + 4] = v1.x; hr[cc * 8 + 5] = v1.y;
        hr[cc * 8 + 6] = v1.z; hr[cc * 8 + 7] = v1.w;
    }
#pragma unroll
    for (int j = 0; j < 8; ++j) red[slot][cc * 8 + j] = acc[j];
    __syncthreads();
    if (tid < 128) {
        float s = 0.f;
#pragma unroll
        for (int g = 0; g < 16; ++g) s += red[g][tid];
        m1[tid] = s * (1.0f / N0);
    }
    __syncthreads();

    // ---- phase 2a: tv = concat(m1, m2) @ W1  (256 -> 128), split-K ---------
    const int c = tid & 127;
    const int h = tid >> 7;
    {
        const float* xh = h ? m2 : m1;
        const float* w = W1 + (size_t)(h * 128) * 128 + c;
        float p = 0.f;
#pragma unroll 8
        for (int k = 0; k < 128; ++k) {
            p += xh[k] * w[(size_t)k * 128];
        }
        red[h][c] = p;
    }
    __syncthreads();
    if (tid < 128) tv[tid] = red[0][tid] + red[1][tid];
    __syncthreads();

    // ---- phase 2b: z = concat(hr, tv) @ W0 + b0; sigmoid -------------------
    {
        const float* yh = h ? tv : hr;
        const float* w = W0 + (size_t)(h * 128) * 128 + c;
        float q = 0.f;
#pragma unroll 8
        for (int k = 0; k < 128; ++k) {
            q += yh[k] * w[(size_t)k * 128];
        }
        red[h][c] = q;
    }
    __syncthreads();
    if (tid < 128) {
        float z = red[0][tid] + red[1][tid] + b0[tid];
        float s = 1.0f / (1.0f + __expf(-z));
        out[(size_t)b * 128 + tid] = s;
    }
}

extern "C" void kernel_launch(void* const* d_in, const int* in_sizes, int n_in,
                              void* d_out, int out_size, void* d_ws, size_t ws_size,
                              hipStream_t stream) {
    const float* emb   = (const float*)d_in[0];
    const float* W0    = (const float*)d_in[1];
    const float* b0    = (const float*)d_in[2];
    const float* W1    = (const float*)d_in[3];
    const int*   roots = (const int*)d_in[4];
    const int*   idx1  = (const int*)d_in[5];
    const int*   idx2  = (const int*)d_in[6];
    float* out = (float*)d_out;

    sage_fused<<<NBATCH, 256, 0, stream>>>(emb, W0, b0, W1, roots, idx1, idx2, out);
}